// Round 1
// baseline (3080.495 us; speedup 1.0000x reference)
//
#include <hip/hip_runtime.h>
#include <hip/hip_bf16.h>

// Problem constants
constexpr int NB = 2;        // batch
constexpr int NT = 4096;     // seq len
constexpr int NH = 16;       // heads
constexpr int ND = 128;      // head dim
constexpr int HID = NH * ND;         // 2048
constexpr int QKV_N = 3 * HID;       // 6144
constexpr int ROWS = NB * NT;        // 8192
constexpr int CHUNK = 128;           // scan chunk length
constexpr int NCH = NT / CHUNK;      // 32 chunks

// ---------------- fp32 tiled SGEMM: C[M,N] = A[M,K] @ B[K,N], row-major ----
#define BM 128
#define BN 128
#define BK 16

__global__ __launch_bounds__(256) void sgemm_kernel(const float* __restrict__ A,
                                                    const float* __restrict__ B,
                                                    float* __restrict__ C,
                                                    int M, int N, int K) {
    __shared__ float As[BK][BM + 4];   // stored transposed [k][m], padded
    __shared__ float Bs[BK][BN];
    const int t  = threadIdx.x;
    const int bm = blockIdx.y * BM;
    const int bn = blockIdx.x * BN;
    const int tx = t & 15;     // 16 col-threads
    const int ty = t >> 4;     // 16 row-threads

    float acc[8][8] = {};

    for (int k0 = 0; k0 < K; k0 += BK) {
        // A tile: 128 rows x 16 k = 512 float4 loads, 2 per thread, row-contiguous
        #pragma unroll
        for (int i = 0; i < 2; ++i) {
            int idx = t + i * 256;
            int row = idx >> 2;
            int kq  = (idx & 3) * 4;
            float4 av = *reinterpret_cast<const float4*>(
                &A[(size_t)(bm + row) * K + k0 + kq]);
            As[kq + 0][row] = av.x;
            As[kq + 1][row] = av.y;
            As[kq + 2][row] = av.z;
            As[kq + 3][row] = av.w;
        }
        // B tile: 16 rows x 128 cols, fully coalesced
        #pragma unroll
        for (int i = 0; i < 2; ++i) {
            int idx = t + i * 256;
            int row = idx >> 5;
            int cq  = (idx & 31) * 4;
            *reinterpret_cast<float4*>(&Bs[row][cq]) =
                *reinterpret_cast<const float4*>(
                    &B[(size_t)(k0 + row) * N + bn + cq]);
        }
        __syncthreads();

        #pragma unroll
        for (int kk = 0; kk < BK; ++kk) {
            float a[8], b[8];
            #pragma unroll
            for (int i = 0; i < 8; ++i) a[i] = As[kk][ty * 8 + i];
            #pragma unroll
            for (int j = 0; j < 8; ++j) b[j] = Bs[kk][tx * 8 + j];
            #pragma unroll
            for (int i = 0; i < 8; ++i)
                #pragma unroll
                for (int j = 0; j < 8; ++j)
                    acc[i][j] = fmaf(a[i], b[j], acc[i][j]);
        }
        __syncthreads();
    }

    #pragma unroll
    for (int i = 0; i < 8; ++i) {
        int row = bm + ty * 8 + i;
        #pragma unroll
        for (int j = 0; j < 8; j += 4) {
            float4 v = make_float4(acc[i][j], acc[i][j + 1], acc[i][j + 2], acc[i][j + 3]);
            *reinterpret_cast<float4*>(&C[(size_t)row * N + bn + tx * 8 + j]) = v;
        }
    }
}

// ---------------- scan helpers ----------------
__device__ inline float phi_f(float z) {              // elu(z)+1
    return z > 0.f ? z + 1.f : __expf(z);
}
__device__ inline float sigmoid_f(float z) {
    return 1.f / (1.f + __expf(-z));
}

// Pass 1: per-(b,h,chunk) local scan finals (zero init).
// grid = NB*NH*NCH blocks, 64 threads; thread owns dims d and d+64.
__global__ void scan_pass1(const float* __restrict__ qkv,
                           const float* __restrict__ decay_param,
                           float* __restrict__ fkv, float* __restrict__ fk) {
    const int blk = blockIdx.x;
    const int c = blk % NCH;
    const int h = (blk / NCH) % NH;
    const int b = blk / (NCH * NH);
    const int lane = threadIdx.x;
    const float dec = sigmoid_f(decay_param[h]);

    float skv0 = 0.f, skv1 = 0.f, sk0 = 0.f, sk1 = 0.f;
    const float* base = qkv + ((size_t)b * NT + (size_t)c * CHUNK) * QKV_N + h * ND;
    for (int t = 0; t < CHUNK; ++t) {
        const float* r = base + (size_t)t * QKV_N;
        float k0 = phi_f(r[HID + lane]);
        float k1 = phi_f(r[HID + lane + 64]);
        float v0 = r[2 * HID + lane];
        float v1 = r[2 * HID + lane + 64];
        skv0 = fmaf(dec, skv0, k0 * v0);
        skv1 = fmaf(dec, skv1, k1 * v1);
        sk0  = fmaf(dec, sk0,  k0);
        sk1  = fmaf(dec, sk1,  k1);
    }
    size_t o = (size_t)blk * ND + lane;   // [b][h][c][d]
    fkv[o] = skv0; fkv[o + 64] = skv1;
    fk[o]  = sk0;  fk[o + 64]  = sk1;
}

// Pass 2: combine chunk finals sequentially; emit per-chunk carry-in and the
// final states (new_kv, new_ksum) straight into d_out.
// grid = NB*NH blocks, 64 threads.
__global__ void scan_pass2(const float* __restrict__ fkv, const float* __restrict__ fk,
                           const float* __restrict__ decay_param,
                           float* __restrict__ ckv, float* __restrict__ ck,
                           float* __restrict__ out_states) {
    const int bh = blockIdx.x;            // b*NH + h
    const int h = bh % NH;
    const int lane = threadIdx.x;
    const float dec = sigmoid_f(decay_param[h]);
    const float dL = powf(dec, (float)CHUNK);

    float Skv0 = 0.f, Skv1 = 0.f, Sk0 = 0.f, Sk1 = 0.f;
    for (int c = 0; c < NCH; ++c) {
        size_t o = ((size_t)bh * NCH + c) * ND + lane;
        ckv[o] = Skv0; ckv[o + 64] = Skv1;
        ck[o]  = Sk0;  ck[o + 64]  = Sk1;
        Skv0 = fmaf(dL, Skv0, fkv[o]);
        Skv1 = fmaf(dL, Skv1, fkv[o + 64]);
        Sk0  = fmaf(dL, Sk0,  fk[o]);
        Sk1  = fmaf(dL, Sk1,  fk[o + 64]);
    }
    size_t so = (size_t)bh * ND + lane;
    out_states[so] = Skv0;                    // new_kv [B,H,D]
    out_states[so + 64] = Skv1;
    out_states[NB * NH * ND + so] = Sk0;      // new_ksum [B,H,D]
    out_states[NB * NH * ND + so + 64] = Sk1;
}

// Pass 3: replay local scan with carry-in, compute den and attn output.
__global__ void scan_pass3(const float* __restrict__ qkv,
                           const float* __restrict__ decay_param,
                           const float* __restrict__ ckv, const float* __restrict__ ck,
                           float* __restrict__ attn) {
    const int blk = blockIdx.x;
    const int c = blk % NCH;
    const int h = (blk / NCH) % NH;
    const int b = blk / (NCH * NH);
    const int lane = threadIdx.x;
    const float dec = sigmoid_f(decay_param[h]);

    size_t co = (size_t)blk * ND + lane;
    float skv0 = ckv[co], skv1 = ckv[co + 64];
    float sk0  = ck[co],  sk1  = ck[co + 64];

    const float* base = qkv + ((size_t)b * NT + (size_t)c * CHUNK) * QKV_N + h * ND;
    float* abase = attn + ((size_t)b * NT + (size_t)c * CHUNK) * HID + h * ND;

    for (int t = 0; t < CHUNK; ++t) {
        const float* r = base + (size_t)t * QKV_N;
        float q0 = phi_f(r[lane]);
        float q1 = phi_f(r[lane + 64]);
        float k0 = phi_f(r[HID + lane]);
        float k1 = phi_f(r[HID + lane + 64]);
        float v0 = r[2 * HID + lane];
        float v1 = r[2 * HID + lane + 64];
        skv0 = fmaf(dec, skv0, k0 * v0);
        skv1 = fmaf(dec, skv1, k1 * v1);
        sk0  = fmaf(dec, sk0,  k0);
        sk1  = fmaf(dec, sk1,  k1);
        float den = fmaf(q0, sk0, q1 * sk1);
        #pragma unroll
        for (int m = 1; m < 64; m <<= 1) den += __shfl_xor(den, m, 64);
        den = fmaxf(den, 1e-6f);
        float inv = 1.f / den;
        float* ar = abase + (size_t)t * HID;
        ar[lane]      = q0 * skv0 * inv;
        ar[lane + 64] = q1 * skv1 * inv;
    }
}

// ---------------- launch ----------------
extern "C" void kernel_launch(void* const* d_in, const int* in_sizes, int n_in,
                              void* d_out, int out_size, void* d_ws, size_t ws_size,
                              hipStream_t stream) {
    const float* x      = (const float*)d_in[0];   // [2,4096,2048]
    const float* w_qkv  = (const float*)d_in[1];   // [2048,6144]
    const float* w_out  = (const float*)d_in[2];   // [2048,2048]
    const float* decayp = (const float*)d_in[3];   // [16]
    float* out = (float*)d_out;

    // workspace layout (floats): qkv | attn | fkv | fk | ckv | ck
    float* ws   = (float*)d_ws;
    float* qkv  = ws;                                    // 50,331,648
    float* attn = ws + (size_t)ROWS * QKV_N;             // 16,777,216
    float* fkv  = attn + (size_t)ROWS * HID;             // 131,072
    float* fk   = fkv + (size_t)NB * NH * NCH * ND;
    float* ckv  = fk  + (size_t)NB * NH * NCH * ND;
    float* ck   = ckv + (size_t)NB * NH * NCH * ND;

    // GEMM1: qkv = x @ w_qkv
    dim3 g1(QKV_N / BN, ROWS / BM);
    sgemm_kernel<<<g1, 256, 0, stream>>>(x, w_qkv, qkv, ROWS, QKV_N, HID);

    // chunked decay scans
    scan_pass1<<<NB * NH * NCH, 64, 0, stream>>>(qkv, decayp, fkv, fk);
    scan_pass2<<<NB * NH, 64, 0, stream>>>(fkv, fk, decayp, ckv, ck,
                                           out + (size_t)ROWS * HID);
    scan_pass3<<<NB * NH * NCH, 64, 0, stream>>>(qkv, decayp, ckv, ck, attn);

    // GEMM2: out = attn @ w_out
    dim3 g2(HID / BN, ROWS / BM);
    sgemm_kernel<<<g2, 256, 0, stream>>>(attn, w_out, out, ROWS, HID, HID);
}

// Round 2
// 514.004 us; speedup vs baseline: 5.9931x; 5.9931x over previous
//
#include <hip/hip_runtime.h>
#include <hip/hip_bf16.h>
#include <stdint.h>

// Problem constants
constexpr int NB = 2;        // batch
constexpr int NT = 4096;     // seq len
constexpr int NH = 16;       // heads
constexpr int ND = 128;      // head dim
constexpr int HID = NH * ND;         // 2048
constexpr int QKV_N = 3 * HID;       // 6144
constexpr int ROWS = NB * NT;        // 8192
constexpr int CHUNK = 128;           // scan chunk length
constexpr int NCH = NT / CHUNK;      // 32 chunks

typedef __bf16 bf16x8 __attribute__((ext_vector_type(8)));
typedef float  f32x4  __attribute__((ext_vector_type(4)));

__device__ inline unsigned short f2bf(float f) {       // RNE fp32->bf16
    unsigned u = __builtin_bit_cast(unsigned, f);
    u += 0x7fffu + ((u >> 16) & 1u);
    return (unsigned short)(u >> 16);
}
__device__ inline float bf2f(unsigned short b) {
    unsigned u = ((unsigned)b) << 16;
    return __builtin_bit_cast(float, u);
}

// ---------------- cast fp32 -> bf16 (flat, float4-vectorized) -------------
__global__ void cast_kernel(const float* __restrict__ in,
                            unsigned short* __restrict__ out, size_t n4) {
    size_t i = blockIdx.x * (size_t)blockDim.x + threadIdx.x;
    size_t stride = (size_t)gridDim.x * blockDim.x;
    for (; i < n4; i += stride) {
        float4 v = reinterpret_cast<const float4*>(in)[i];
        ushort4 o;
        o.x = f2bf(v.x); o.y = f2bf(v.y); o.z = f2bf(v.z); o.w = f2bf(v.w);
        reinterpret_cast<ushort4*>(out)[i] = o;
    }
}

// ------------- transpose + cast: in f32 [R][Cn] -> out bf16 [Cn][R] -------
__global__ __launch_bounds__(256) void transpose_cast(
        const float* __restrict__ in, unsigned short* __restrict__ out,
        int R, int Cn) {
    __shared__ float tile[32][33];
    const int c  = threadIdx.x & 31;
    const int r8 = threadIdx.x >> 5;          // 0..7
    const int r0 = blockIdx.y * 32, c0 = blockIdx.x * 32;
    #pragma unroll
    for (int i = 0; i < 32; i += 8)
        tile[r8 + i][c] = in[(size_t)(r0 + r8 + i) * Cn + c0 + c];
    __syncthreads();
    #pragma unroll
    for (int i = 0; i < 32; i += 8)
        out[(size_t)(c0 + r8 + i) * R + r0 + c] = f2bf(tile[c][r8 + i]);
}

// ---------------- bf16 MFMA GEMM: C[M,N] = A[M,K] @ Bt[N,K]^T --------------
// m97 structure: 128x128 tile, BK=32, 4 waves (2x2), 4x4 16x16x32 frags/wave,
// global_load_lds width-16 staging, 2-barrier K-loop.
template <typename OUT_T>
__global__ __launch_bounds__(256) void gemm_bt(
        const unsigned short* __restrict__ A,   // [M][K] bf16
        const unsigned short* __restrict__ Bt,  // [N][K] bf16
        OUT_T* __restrict__ C,                  // [M][N]
        int M, int N, int K) {
    constexpr int BM = 128, BN = 128, BK = 32;
    __shared__ unsigned short As[BM * BK];   // [128][32] row-major
    __shared__ unsigned short Bs[BN * BK];   // [128][32] (C-cols major)

    const int tid  = threadIdx.x;
    const int wid  = tid >> 6;
    const int lane = tid & 63;
    const int wr   = wid >> 1, wc = wid & 1;
    const int bm   = blockIdx.y * BM, bn = blockIdx.x * BN;

    // staging geometry: round r in {0,1}; lane covers 16B
    const int st_row = wid * 16 + (lane >> 2);    // within 64-row half
    const int st_col = (lane & 3) * 8;
    const unsigned short* gA0 = A  + (size_t)(bm + st_row) * K + st_col;
    const unsigned short* gA1 = gA0 + (size_t)64 * K;
    const unsigned short* gB0 = Bt + (size_t)(bn + st_row) * K + st_col;
    const unsigned short* gB1 = gB0 + (size_t)64 * K;

    const int fr = lane & 15, fq = lane >> 4;

    f32x4 acc[4][4] = {};

    for (int k0 = 0; k0 < K; k0 += BK) {
        __builtin_amdgcn_global_load_lds(
            (const __attribute__((address_space(1))) void*)(gA0 + k0),
            (__attribute__((address_space(3))) void*)&As[wid * 512], 16, 0, 0);
        __builtin_amdgcn_global_load_lds(
            (const __attribute__((address_space(1))) void*)(gA1 + k0),
            (__attribute__((address_space(3))) void*)&As[2048 + wid * 512], 16, 0, 0);
        __builtin_amdgcn_global_load_lds(
            (const __attribute__((address_space(1))) void*)(gB0 + k0),
            (__attribute__((address_space(3))) void*)&Bs[wid * 512], 16, 0, 0);
        __builtin_amdgcn_global_load_lds(
            (const __attribute__((address_space(1))) void*)(gB1 + k0),
            (__attribute__((address_space(3))) void*)&Bs[2048 + wid * 512], 16, 0, 0);
        __syncthreads();

        bf16x8 af[4], bfr[4];
        #pragma unroll
        for (int m = 0; m < 4; ++m) {
            int row = wr * 64 + m * 16 + fr;
            af[m] = *reinterpret_cast<const bf16x8*>(&As[row * 32 + fq * 8]);
        }
        #pragma unroll
        for (int n = 0; n < 4; ++n) {
            int row = wc * 64 + n * 16 + fr;
            bfr[n] = *reinterpret_cast<const bf16x8*>(&Bs[row * 32 + fq * 8]);
        }
        #pragma unroll
        for (int m = 0; m < 4; ++m)
            #pragma unroll
            for (int n = 0; n < 4; ++n)
                acc[m][n] = __builtin_amdgcn_mfma_f32_16x16x32_bf16(
                    af[m], bfr[n], acc[m][n], 0, 0, 0);
        __syncthreads();
    }

    #pragma unroll
    for (int m = 0; m < 4; ++m) {
        #pragma unroll
        for (int n = 0; n < 4; ++n) {
            #pragma unroll
            for (int r = 0; r < 4; ++r) {
                int row = bm + wr * 64 + m * 16 + fq * 4 + r;
                int col = bn + wc * 64 + n * 16 + fr;
                float v = acc[m][n][r];
                if constexpr (sizeof(OUT_T) == 2)
                    C[(size_t)row * N + col] = (OUT_T)f2bf(v);
                else
                    C[(size_t)row * N + col] = (OUT_T)v;
            }
        }
    }
}

// ---------------- scan helpers ----------------
__device__ inline float phi_f(float z) { return z > 0.f ? z + 1.f : __expf(z); }
__device__ inline float sigmoid_f(float z) { return 1.f / (1.f + __expf(-z)); }

// Pass 1: per-(b,h,chunk) local scan finals (zero init). qkv is bf16.
__global__ void scan_pass1(const unsigned short* __restrict__ qkv,
                           const float* __restrict__ decay_param,
                           float* __restrict__ fkv, float* __restrict__ fk) {
    const int blk = blockIdx.x;
    const int c = blk % NCH;
    const int h = (blk / NCH) % NH;
    const int b = blk / (NCH * NH);
    const int lane = threadIdx.x;
    const float dec = sigmoid_f(decay_param[h]);

    float skv0 = 0.f, skv1 = 0.f, sk0 = 0.f, sk1 = 0.f;
    const unsigned short* base =
        qkv + ((size_t)b * NT + (size_t)c * CHUNK) * QKV_N + h * ND;
    for (int t = 0; t < CHUNK; ++t) {
        const unsigned short* r = base + (size_t)t * QKV_N;
        float k0 = phi_f(bf2f(r[HID + lane]));
        float k1 = phi_f(bf2f(r[HID + lane + 64]));
        float v0 = bf2f(r[2 * HID + lane]);
        float v1 = bf2f(r[2 * HID + lane + 64]);
        skv0 = fmaf(dec, skv0, k0 * v0);
        skv1 = fmaf(dec, skv1, k1 * v1);
        sk0  = fmaf(dec, sk0,  k0);
        sk1  = fmaf(dec, sk1,  k1);
    }
    size_t o = (size_t)blk * ND + lane;
    fkv[o] = skv0; fkv[o + 64] = skv1;
    fk[o]  = sk0;  fk[o + 64]  = sk1;
}

// Pass 2: sequential chunk combine; emits carry-ins and final states.
__global__ void scan_pass2(const float* __restrict__ fkv, const float* __restrict__ fk,
                           const float* __restrict__ decay_param,
                           float* __restrict__ ckv, float* __restrict__ ck,
                           float* __restrict__ out_states) {
    const int bh = blockIdx.x;
    const int h = bh % NH;
    const int lane = threadIdx.x;
    const float dec = sigmoid_f(decay_param[h]);
    const float dL = powf(dec, (float)CHUNK);

    float Skv0 = 0.f, Skv1 = 0.f, Sk0 = 0.f, Sk1 = 0.f;
    for (int c = 0; c < NCH; ++c) {
        size_t o = ((size_t)bh * NCH + c) * ND + lane;
        ckv[o] = Skv0; ckv[o + 64] = Skv1;
        ck[o]  = Sk0;  ck[o + 64]  = Sk1;
        Skv0 = fmaf(dL, Skv0, fkv[o]);
        Skv1 = fmaf(dL, Skv1, fkv[o + 64]);
        Sk0  = fmaf(dL, Sk0,  fk[o]);
        Sk1  = fmaf(dL, Sk1,  fk[o + 64]);
    }
    size_t so = (size_t)bh * ND + lane;
    out_states[so] = Skv0;
    out_states[so + 64] = Skv1;
    out_states[NB * NH * ND + so] = Sk0;
    out_states[NB * NH * ND + so + 64] = Sk1;
}

// Pass 3: replay with carry-in; writes attn in bf16.
__global__ void scan_pass3(const unsigned short* __restrict__ qkv,
                           const float* __restrict__ decay_param,
                           const float* __restrict__ ckv, const float* __restrict__ ck,
                           unsigned short* __restrict__ attn) {
    const int blk = blockIdx.x;
    const int c = blk % NCH;
    const int h = (blk / NCH) % NH;
    const int b = blk / (NCH * NH);
    const int lane = threadIdx.x;
    const float dec = sigmoid_f(decay_param[h]);

    size_t co = (size_t)blk * ND + lane;
    float skv0 = ckv[co], skv1 = ckv[co + 64];
    float sk0  = ck[co],  sk1  = ck[co + 64];

    const unsigned short* base =
        qkv + ((size_t)b * NT + (size_t)c * CHUNK) * QKV_N + h * ND;
    unsigned short* abase =
        attn + ((size_t)b * NT + (size_t)c * CHUNK) * HID + h * ND;

    for (int t = 0; t < CHUNK; ++t) {
        const unsigned short* r = base + (size_t)t * QKV_N;
        float q0 = phi_f(bf2f(r[lane]));
        float q1 = phi_f(bf2f(r[lane + 64]));
        float k0 = phi_f(bf2f(r[HID + lane]));
        float k1 = phi_f(bf2f(r[HID + lane + 64]));
        float v0 = bf2f(r[2 * HID + lane]);
        float v1 = bf2f(r[2 * HID + lane + 64]);
        skv0 = fmaf(dec, skv0, k0 * v0);
        skv1 = fmaf(dec, skv1, k1 * v1);
        sk0  = fmaf(dec, sk0,  k0);
        sk1  = fmaf(dec, sk1,  k1);
        float den = fmaf(q0, sk0, q1 * sk1);
        #pragma unroll
        for (int m = 1; m < 64; m <<= 1) den += __shfl_xor(den, m, 64);
        den = fmaxf(den, 1e-6f);
        float inv = 1.f / den;
        unsigned short* ar = abase + (size_t)t * HID;
        ar[lane]      = f2bf(q0 * skv0 * inv);
        ar[lane + 64] = f2bf(q1 * skv1 * inv);
    }
}

// ---------------- launch ----------------
extern "C" void kernel_launch(void* const* d_in, const int* in_sizes, int n_in,
                              void* d_out, int out_size, void* d_ws, size_t ws_size,
                              hipStream_t stream) {
    const float* x      = (const float*)d_in[0];   // [2,4096,2048]
    const float* w_qkv  = (const float*)d_in[1];   // [2048,6144]
    const float* w_out  = (const float*)d_in[2];   // [2048,2048]
    const float* decayp = (const float*)d_in[3];   // [16]
    float* out = (float*)d_out;

    // workspace layout (ushort/float segments, all 16B-aligned sizes)
    char* ws = (char*)d_ws;
    unsigned short* xb     = (unsigned short*)ws;                         // 8192*2048
    unsigned short* wqkvT  = xb    + (size_t)ROWS * HID;                  // 6144*2048
    unsigned short* woutT  = wqkvT + (size_t)QKV_N * HID;                 // 2048*2048
    unsigned short* qkvb   = woutT + (size_t)HID * HID;                   // 8192*6144
    unsigned short* attnb  = qkvb  + (size_t)ROWS * QKV_N;                // 8192*2048
    float* fkv = (float*)(attnb + (size_t)ROWS * HID);
    float* fk  = fkv + (size_t)NB * NH * NCH * ND;
    float* ckv = fk  + (size_t)NB * NH * NCH * ND;
    float* ck  = ckv + (size_t)NB * NH * NCH * ND;

    // casts
    cast_kernel<<<2048, 256, 0, stream>>>(x, xb, (size_t)ROWS * HID / 4);
    dim3 tg1(QKV_N / 32, HID / 32);
    transpose_cast<<<tg1, 256, 0, stream>>>(w_qkv, wqkvT, HID, QKV_N);
    dim3 tg2(HID / 32, HID / 32);
    transpose_cast<<<tg2, 256, 0, stream>>>(w_out, woutT, HID, HID);

    // GEMM1: qkvb = xb @ wqkvT^T   (bf16 out)
    dim3 g1(QKV_N / 128, ROWS / 128);
    gemm_bt<unsigned short><<<g1, 256, 0, stream>>>(xb, wqkvT, qkvb,
                                                    ROWS, QKV_N, HID);

    // chunked decay scans
    scan_pass1<<<NB * NH * NCH, 64, 0, stream>>>(qkvb, decayp, fkv, fk);
    scan_pass2<<<NB * NH, 64, 0, stream>>>(fkv, fk, decayp, ckv, ck,
                                           out + (size_t)ROWS * HID);
    scan_pass3<<<NB * NH * NCH, 64, 0, stream>>>(qkvb, decayp, ckv, ck, attnb);

    // GEMM2: out = attnb @ woutT^T  (f32 out)
    dim3 g2(HID / 128, ROWS / 128);
    gemm_bt<float><<<g2, 256, 0, stream>>>(attnb, woutT, out,
                                           ROWS, HID, HID);
}

// Round 3
// 435.927 us; speedup vs baseline: 7.0665x; 1.1791x over previous
//
#include <hip/hip_runtime.h>
#include <hip/hip_bf16.h>
#include <stdint.h>

// Problem constants
constexpr int NB = 2;        // batch
constexpr int NT = 4096;     // seq len
constexpr int NH = 16;       // heads
constexpr int ND = 128;      // head dim
constexpr int HID = NH * ND;         // 2048
constexpr int QKV_N = 3 * HID;       // 6144
constexpr int ROWS = NB * NT;        // 8192
constexpr int CHUNK = 64;            // scan chunk length
constexpr int NCH = NT / CHUNK;      // 64 chunks

typedef __bf16 bf16x8 __attribute__((ext_vector_type(8)));
typedef float  f32x4  __attribute__((ext_vector_type(4)));

__device__ inline unsigned short f2bf(float f) {       // RNE fp32->bf16
    unsigned u = __builtin_bit_cast(unsigned, f);
    u += 0x7fffu + ((u >> 16) & 1u);
    return (unsigned short)(u >> 16);
}
__device__ inline float bf2f(unsigned short b) {
    unsigned u = ((unsigned)b) << 16;
    return __builtin_bit_cast(float, u);
}

// ---------------- cast fp32 -> bf16 (flat, float4-vectorized) -------------
__global__ void cast_kernel(const float* __restrict__ in,
                            unsigned short* __restrict__ out, size_t n4) {
    size_t i = blockIdx.x * (size_t)blockDim.x + threadIdx.x;
    size_t stride = (size_t)gridDim.x * blockDim.x;
    for (; i < n4; i += stride) {
        float4 v = reinterpret_cast<const float4*>(in)[i];
        ushort4 o;
        o.x = f2bf(v.x); o.y = f2bf(v.y); o.z = f2bf(v.z); o.w = f2bf(v.w);
        reinterpret_cast<ushort4*>(out)[i] = o;
    }
}

// ------------- transpose + cast: in f32 [R][Cn] -> out bf16 [Cn][R] -------
__global__ __launch_bounds__(256) void transpose_cast(
        const float* __restrict__ in, unsigned short* __restrict__ out,
        int R, int Cn) {
    __shared__ float tile[32][33];
    const int c  = threadIdx.x & 31;
    const int r8 = threadIdx.x >> 5;          // 0..7
    const int r0 = blockIdx.y * 32, c0 = blockIdx.x * 32;
    #pragma unroll
    for (int i = 0; i < 32; i += 8)
        tile[r8 + i][c] = in[(size_t)(r0 + r8 + i) * Cn + c0 + c];
    __syncthreads();
    #pragma unroll
    for (int i = 0; i < 32; i += 8)
        out[(size_t)(c0 + r8 + i) * R + r0 + c] = f2bf(tile[c][r8 + i]);
}

// =================== 256x256 8-wave 4-phase-per-K-tile GEMM =================
// C[M,N] = A[M,K] @ Bt[N,K]^T, bf16 in, fp32 acc.
// T2: LDS XOR swizzle (slot ^= row&7) via inverse-swizzled global source +
//     linear global_load_lds dest, same involution on ds_read.
// T3/T4: one sub-tile staged per phase into the buffer consumed LAST
//     iteration; counted vmcnt(4) per phase (drains exactly the sub the
//     next phase reads); epilogue drains 4->2->0. Raw s_barrier (no
//     __syncthreads - that would emit vmcnt(0)).
// T5: setprio(1) around each 16-MFMA quadrant cluster.

#define WAITV(N) asm volatile("s_waitcnt vmcnt(" #N ")" ::: "memory")
#define FENCE()  asm volatile("" ::: "memory")

__device__ __forceinline__ void gll(const unsigned short* src, unsigned short* dst) {
    __builtin_amdgcn_global_load_lds(
        (const __attribute__((address_space(1))) void*)src,
        (__attribute__((address_space(3))) void*)dst, 16, 0, 0);
}

// A sub 0 = rows {[0,64) u [128,192)} (mh0 rows of both wm); sub 1 = +64.
__device__ __forceinline__ void stage_a(const unsigned short* Ag, int K, int k0,
                                        unsigned short* lds, int sub,
                                        int wid, int lane) {
    const int rl = wid * 8 + (lane >> 3);
    const int ce = ((lane & 7) ^ (lane >> 3)) * 8;   // inverse-swizzled col
    #pragma unroll
    for (int j = 0; j < 2; ++j) {
        int row = j * 128 + sub * 64;
        gll(Ag + (size_t)(row + rl) * K + k0 + ce,
            lds + (row + wid * 8) * 64);
    }
}
// B sub 0 = rows {wn*64+[0,32)} all wn (nh0); sub 1 = +32 (nh1).
__device__ __forceinline__ void stage_b(const unsigned short* Bg, int K, int k0,
                                        unsigned short* lds, int sub,
                                        int wid, int lane) {
    const int ce = ((lane & 7) ^ (lane >> 3)) * 8;
    const int rb = (wid >> 2) * 64 + sub * 32 + (wid & 3) * 8;
    #pragma unroll
    for (int j = 0; j < 2; ++j) {
        int rowbase = j * 128 + rb;
        gll(Bg + (size_t)(rowbase + (lane >> 3)) * K + k0 + ce,
            lds + rowbase * 64);
    }
}

__device__ __forceinline__ bf16x8 ld_frag(const unsigned short* tile,
                                          int r, int kk, int fq) {
    int slot = (kk * 4 + fq) ^ (r & 7);          // swizzled 16B slot
    return *reinterpret_cast<const bf16x8*>(tile + r * 64 + slot * 8);
}

template <int MH>
__device__ __forceinline__ void read_a(const unsigned short* T, int wm,
                                       int fr, int fq, bf16x8 af[4][2]) {
    #pragma unroll
    for (int m = 0; m < 4; ++m) {
        int r = wm * 128 + MH * 64 + m * 16 + fr;
        af[m][0] = ld_frag(T, r, 0, fq);
        af[m][1] = ld_frag(T, r, 1, fq);
    }
}
template <int NHH>
__device__ __forceinline__ void read_b(const unsigned short* T, int wn,
                                       int fr, int fq, bf16x8 bfr[4][2]) {
    #pragma unroll
    for (int n = 0; n < 2; ++n) {
        int r = wn * 64 + NHH * 32 + n * 16 + fr;
        bfr[NHH * 2 + n][0] = ld_frag(T, r, 0, fq);
        bfr[NHH * 2 + n][1] = ld_frag(T, r, 1, fq);
    }
}

template <int MH, int NHH>
__device__ __forceinline__ void mfma_quad(f32x4 acc[8][4],
                                          bf16x8 af[4][2], bf16x8 bfr[4][2]) {
    __builtin_amdgcn_s_setprio(1);
    #pragma unroll
    for (int kk = 0; kk < 2; ++kk)
        #pragma unroll
        for (int m = 0; m < 4; ++m)
            #pragma unroll
            for (int n = 0; n < 2; ++n)
                acc[MH * 4 + m][NHH * 2 + n] =
                    __builtin_amdgcn_mfma_f32_16x16x32_bf16(
                        af[m][kk], bfr[NHH * 2 + n][kk],
                        acc[MH * 4 + m][NHH * 2 + n], 0, 0, 0);
    __builtin_amdgcn_s_setprio(0);
}

template <typename OUT_T>
__global__ __launch_bounds__(512, 2) void gemm256(
        const unsigned short* __restrict__ A,   // [M][K] bf16
        const unsigned short* __restrict__ Bt,  // [N][K] bf16
        OUT_T* __restrict__ C,                  // [M][N]
        int M, int N, int K, int nbx, int cpx) {
    __shared__ unsigned short As[2][256 * 64];
    __shared__ unsigned short Bs[2][256 * 64];

    const int bid = blockIdx.x;
    const int wk  = (bid & 7) * cpx + (bid >> 3);   // T1 XCD swizzle
    const int bx  = wk % nbx, by = wk / nbx;
    const int tid = threadIdx.x, wid = tid >> 6, lane = tid & 63;
    const int wm  = wid >> 2, wn = wid & 3;
    const int fr  = lane & 15, fq = lane >> 4;

    const unsigned short* Ag = A  + (size_t)by * 256 * K;
    const unsigned short* Bg = Bt + (size_t)bx * 256 * K;

    // prologue: stage tile 0 in steady-state issue order
    stage_a(Ag, K, 0, As[0], 0, wid, lane);
    stage_b(Bg, K, 0, Bs[0], 0, wid, lane);
    stage_b(Bg, K, 0, Bs[0], 1, wid, lane);
    stage_a(Ag, K, 0, As[0], 1, wid, lane);

    f32x4 acc[8][4] = {};
    bf16x8 af[4][2], bfr[4][2];

    const int NK = K / 64;
    for (int t = 0; t < NK - 1; ++t) {
        const unsigned short* Ac = As[t & 1];
        const unsigned short* Bc = Bs[t & 1];
        unsigned short* An = As[(t + 1) & 1];
        unsigned short* Bn = Bs[(t + 1) & 1];
        const int k1 = (t + 1) * 64;
        // phase 1: quadrant (mh0,nh0)
        WAITV(4); __builtin_amdgcn_s_barrier(); FENCE();
        stage_a(Ag, K, k1, An, 0, wid, lane);
        read_a<0>(Ac, wm, fr, fq, af);
        read_b<0>(Bc, wn, fr, fq, bfr);
        mfma_quad<0, 0>(acc, af, bfr);
        // phase 2: (mh0,nh1)
        WAITV(4); __builtin_amdgcn_s_barrier(); FENCE();
        stage_b(Bg, K, k1, Bn, 0, wid, lane);
        read_b<1>(Bc, wn, fr, fq, bfr);
        mfma_quad<0, 1>(acc, af, bfr);
        // phase 3: (mh1,nh1)
        WAITV(4); __builtin_amdgcn_s_barrier(); FENCE();
        stage_b(Bg, K, k1, Bn, 1, wid, lane);
        read_a<1>(Ac, wm, fr, fq, af);
        mfma_quad<1, 1>(acc, af, bfr);
        // phase 4: (mh1,nh0) — all data already resident
        __builtin_amdgcn_s_barrier(); FENCE();
        stage_a(Ag, K, k1, An, 1, wid, lane);
        mfma_quad<1, 0>(acc, af, bfr);
    }
    {   // last K-tile: no staging; drain 4 -> 2 -> 0
        const unsigned short* Ac = As[(NK - 1) & 1];
        const unsigned short* Bc = Bs[(NK - 1) & 1];
        WAITV(4); __builtin_amdgcn_s_barrier(); FENCE();
        read_a<0>(Ac, wm, fr, fq, af);
        read_b<0>(Bc, wn, fr, fq, bfr);
        mfma_quad<0, 0>(acc, af, bfr);
        WAITV(2); __builtin_amdgcn_s_barrier(); FENCE();
        read_b<1>(Bc, wn, fr, fq, bfr);
        mfma_quad<0, 1>(acc, af, bfr);
        WAITV(0); __builtin_amdgcn_s_barrier(); FENCE();
        read_a<1>(Ac, wm, fr, fq, af);
        mfma_quad<1, 1>(acc, af, bfr);
        mfma_quad<1, 0>(acc, af, bfr);
    }

    // epilogue C write (verified C/D layout: row = fq*4+r, col = fr)
    const int bm = by * 256, bn = bx * 256;
    #pragma unroll
    for (int m = 0; m < 8; ++m) {
        #pragma unroll
        for (int n = 0; n < 4; ++n) {
            #pragma unroll
            for (int r = 0; r < 4; ++r) {
                int row = bm + wm * 128 + m * 16 + fq * 4 + r;
                int col = bn + wn * 64 + n * 16 + fr;
                float v = acc[m][n][r];
                if constexpr (sizeof(OUT_T) == 2)
                    C[(size_t)row * N + col] = (OUT_T)f2bf(v);
                else
                    C[(size_t)row * N + col] = (OUT_T)v;
            }
        }
    }
}

// ---------------- scan helpers ----------------
__device__ inline float phi_f(float z) { return z > 0.f ? z + 1.f : __expf(z); }
__device__ inline float sigmoid_f(float z) { return 1.f / (1.f + __expf(-z)); }

// Pass 1: per-(b,h,chunk) local scan finals (zero init). qkv bf16.
// lane owns dims {2*lane, 2*lane+1} (paired 4B loads).
__global__ void scan_pass1(const unsigned short* __restrict__ qkv,
                           const float* __restrict__ decay_param,
                           float* __restrict__ fkv, float* __restrict__ fk) {
    const int blk = blockIdx.x;
    const int c = blk % NCH;
    const int h = (blk / NCH) % NH;
    const int b = blk / (NCH * NH);
    const int lane = threadIdx.x;
    const float dec = sigmoid_f(decay_param[h]);

    float skv0 = 0.f, skv1 = 0.f, sk0 = 0.f, sk1 = 0.f;
    const unsigned short* base =
        qkv + ((size_t)b * NT + (size_t)c * CHUNK) * QKV_N + h * ND;
    for (int t = 0; t < CHUNK; ++t) {
        const unsigned short* r = base + (size_t)t * QKV_N;
        unsigned kp = *reinterpret_cast<const unsigned*>(r + HID + 2 * lane);
        unsigned vp = *reinterpret_cast<const unsigned*>(r + 2 * HID + 2 * lane);
        float k0 = phi_f(bf2f((unsigned short)(kp & 0xffff)));
        float k1 = phi_f(bf2f((unsigned short)(kp >> 16)));
        float v0 = bf2f((unsigned short)(vp & 0xffff));
        float v1 = bf2f((unsigned short)(vp >> 16));
        skv0 = fmaf(dec, skv0, k0 * v0);
        skv1 = fmaf(dec, skv1, k1 * v1);
        sk0  = fmaf(dec, sk0,  k0);
        sk1  = fmaf(dec, sk1,  k1);
    }
    size_t o = (size_t)blk * ND + 2 * lane;
    *reinterpret_cast<float2*>(&fkv[o]) = make_float2(skv0, skv1);
    *reinterpret_cast<float2*>(&fk[o])  = make_float2(sk0, sk1);
}

// Pass 2: sequential chunk combine; emits carry-ins and final states.
__global__ void scan_pass2(const float* __restrict__ fkv, const float* __restrict__ fk,
                           const float* __restrict__ decay_param,
                           float* __restrict__ ckv, float* __restrict__ ck,
                           float* __restrict__ out_states) {
    const int bh = blockIdx.x;
    const int h = bh % NH;
    const int lane = threadIdx.x;
    const float dec = sigmoid_f(decay_param[h]);
    const float dL = powf(dec, (float)CHUNK);

    float Skv0 = 0.f, Skv1 = 0.f, Sk0 = 0.f, Sk1 = 0.f;
    for (int c = 0; c < NCH; ++c) {
        size_t o = ((size_t)bh * NCH + c) * ND + 2 * lane;
        *reinterpret_cast<float2*>(&ckv[o]) = make_float2(Skv0, Skv1);
        *reinterpret_cast<float2*>(&ck[o])  = make_float2(Sk0, Sk1);
        float2 fv = *reinterpret_cast<const float2*>(&fkv[o]);
        float2 fs = *reinterpret_cast<const float2*>(&fk[o]);
        Skv0 = fmaf(dL, Skv0, fv.x);
        Skv1 = fmaf(dL, Skv1, fv.y);
        Sk0  = fmaf(dL, Sk0,  fs.x);
        Sk1  = fmaf(dL, Sk1,  fs.y);
    }
    size_t so = (size_t)bh * ND + 2 * lane;
    *reinterpret_cast<float2*>(&out_states[so]) = make_float2(Skv0, Skv1);
    *reinterpret_cast<float2*>(&out_states[NB * NH * ND + so]) = make_float2(Sk0, Sk1);
}

// Pass 3: replay with carry-in; writes attn in bf16.
__global__ void scan_pass3(const unsigned short* __restrict__ qkv,
                           const float* __restrict__ decay_param,
                           const float* __restrict__ ckv, const float* __restrict__ ck,
                           unsigned short* __restrict__ attn) {
    const int blk = blockIdx.x;
    const int c = blk % NCH;
    const int h = (blk / NCH) % NH;
    const int b = blk / (NCH * NH);
    const int lane = threadIdx.x;
    const float dec = sigmoid_f(decay_param[h]);

    size_t co = (size_t)blk * ND + 2 * lane;
    float2 cv = *reinterpret_cast<const float2*>(&ckv[co]);
    float2 cs = *reinterpret_cast<const float2*>(&ck[co]);
    float skv0 = cv.x, skv1 = cv.y, sk0 = cs.x, sk1 = cs.y;

    const unsigned short* base =
        qkv + ((size_t)b * NT + (size_t)c * CHUNK) * QKV_N + h * ND;
    unsigned short* abase =
        attn + ((size_t)b * NT + (size_t)c * CHUNK) * HID + h * ND;

    for (int t = 0; t < CHUNK; ++t) {
        const unsigned short* r = base + (size_t)t * QKV_N;
        unsigned qp = *reinterpret_cast<const unsigned*>(r + 2 * lane);
        unsigned kp = *reinterpret_cast<const unsigned*>(r + HID + 2 * lane);
        unsigned vp = *reinterpret_cast<const unsigned*>(r + 2 * HID + 2 * lane);
        float q0 = phi_f(bf2f((unsigned short)(qp & 0xffff)));
        float q1 = phi_f(bf2f((unsigned short)(qp >> 16)));
        float k0 = phi_f(bf2f((unsigned short)(kp & 0xffff)));
        float k1 = phi_f(bf2f((unsigned short)(kp >> 16)));
        float v0 = bf2f((unsigned short)(vp & 0xffff));
        float v1 = bf2f((unsigned short)(vp >> 16));
        skv0 = fmaf(dec, skv0, k0 * v0);
        skv1 = fmaf(dec, skv1, k1 * v1);
        sk0  = fmaf(dec, sk0,  k0);
        sk1  = fmaf(dec, sk1,  k1);
        float den = fmaf(q0, sk0, q1 * sk1);
        #pragma unroll
        for (int m = 1; m < 64; m <<= 1) den += __shfl_xor(den, m, 64);
        den = fmaxf(den, 1e-6f);
        float inv = 1.f / den;
        unsigned o = ((unsigned)f2bf(q1 * skv1 * inv) << 16) |
                     (unsigned)f2bf(q0 * skv0 * inv);
        *reinterpret_cast<unsigned*>(abase + (size_t)t * HID + 2 * lane) = o;
    }
}

// ---------------- launch ----------------
extern "C" void kernel_launch(void* const* d_in, const int* in_sizes, int n_in,
                              void* d_out, int out_size, void* d_ws, size_t ws_size,
                              hipStream_t stream) {
    const float* x      = (const float*)d_in[0];   // [2,4096,2048]
    const float* w_qkv  = (const float*)d_in[1];   // [2048,6144]
    const float* w_out  = (const float*)d_in[2];   // [2048,2048]
    const float* decayp = (const float*)d_in[3];   // [16]
    float* out = (float*)d_out;

    // workspace layout
    char* ws = (char*)d_ws;
    unsigned short* xb     = (unsigned short*)ws;                         // 8192*2048
    unsigned short* wqkvT  = xb    + (size_t)ROWS * HID;                  // 6144*2048
    unsigned short* woutT  = wqkvT + (size_t)QKV_N * HID;                 // 2048*2048
    unsigned short* qkvb   = woutT + (size_t)HID * HID;                   // 8192*6144
    unsigned short* attnb  = qkvb  + (size_t)ROWS * QKV_N;                // 8192*2048
    float* fkv = (float*)(attnb + (size_t)ROWS * HID);
    float* fk  = fkv + (size_t)NB * NH * NCH * ND;
    float* ckv = fk  + (size_t)NB * NH * NCH * ND;
    float* ck  = ckv + (size_t)NB * NH * NCH * ND;

    // casts
    cast_kernel<<<2048, 256, 0, stream>>>(x, xb, (size_t)ROWS * HID / 4);
    dim3 tg1(QKV_N / 32, HID / 32);
    transpose_cast<<<tg1, 256, 0, stream>>>(w_qkv, wqkvT, HID, QKV_N);
    dim3 tg2(HID / 32, HID / 32);
    transpose_cast<<<tg2, 256, 0, stream>>>(w_out, woutT, HID, HID);

    // GEMM1: qkvb = xb @ wqkvT^T   (bf16 out)  grid 32x24=768
    {
        int nbx = QKV_N / 256, nwg = (ROWS / 256) * nbx;
        gemm256<unsigned short><<<nwg, 512, 0, stream>>>(
            xb, wqkvT, qkvb, ROWS, QKV_N, HID, nbx, nwg / 8);
    }

    // chunked decay scans
    scan_pass1<<<NB * NH * NCH, 64, 0, stream>>>(qkvb, decayp, fkv, fk);
    scan_pass2<<<NB * NH, 64, 0, stream>>>(fkv, fk, decayp, ckv, ck,
                                           out + (size_t)ROWS * HID);
    scan_pass3<<<NB * NH * NCH, 64, 0, stream>>>(qkvb, decayp, ckv, ck, attnb);

    // GEMM2: out = attnb @ woutT^T  (f32 out)  grid 32x8=256
    {
        int nbx = HID / 256, nwg = (ROWS / 256) * nbx;
        gemm256<float><<<nwg, 512, 0, stream>>>(
            attnb, woutT, out, ROWS, HID, HID, nbx, nwg / 8);
    }
}

// Round 4
// 388.288 us; speedup vs baseline: 7.9335x; 1.1227x over previous
//
#include <hip/hip_runtime.h>
#include <hip/hip_bf16.h>
#include <stdint.h>

// Problem constants
constexpr int NB = 2;        // batch
constexpr int NT = 4096;     // seq len
constexpr int NH = 16;       // heads
constexpr int ND = 128;      // head dim
constexpr int HID = NH * ND;         // 2048
constexpr int QKV_N = 3 * HID;       // 6144
constexpr int ROWS = NB * NT;        // 8192
constexpr int CHUNK = 64;            // scan chunk length
constexpr int NCH = NT / CHUNK;      // 64 chunks

typedef __bf16 bf16x8 __attribute__((ext_vector_type(8)));
typedef float  f32x4  __attribute__((ext_vector_type(4)));

__device__ inline unsigned short f2bf(float f) {       // RNE fp32->bf16
    unsigned u = __builtin_bit_cast(unsigned, f);
    u += 0x7fffu + ((u >> 16) & 1u);
    return (unsigned short)(u >> 16);
}
__device__ inline float bf2f(unsigned short b) {
    unsigned u = ((unsigned)b) << 16;
    return __builtin_bit_cast(float, u);
}

// ---------------- cast fp32 -> bf16 (flat, float4-vectorized) -------------
__global__ void cast_kernel(const float* __restrict__ in,
                            unsigned short* __restrict__ out, size_t n4) {
    size_t i = blockIdx.x * (size_t)blockDim.x + threadIdx.x;
    size_t stride = (size_t)gridDim.x * blockDim.x;
    for (; i < n4; i += stride) {
        float4 v = reinterpret_cast<const float4*>(in)[i];
        ushort4 o;
        o.x = f2bf(v.x); o.y = f2bf(v.y); o.z = f2bf(v.z); o.w = f2bf(v.w);
        reinterpret_cast<ushort4*>(out)[i] = o;
    }
}

// ------------- transpose + cast: in f32 [R][Cn] -> out bf16 [Cn][R] -------
__global__ __launch_bounds__(256) void transpose_cast(
        const float* __restrict__ in, unsigned short* __restrict__ out,
        int R, int Cn) {
    __shared__ float tile[32][33];
    const int c  = threadIdx.x & 31;
    const int r8 = threadIdx.x >> 5;          // 0..7
    const int r0 = blockIdx.y * 32, c0 = blockIdx.x * 32;
    #pragma unroll
    for (int i = 0; i < 32; i += 8)
        tile[r8 + i][c] = in[(size_t)(r0 + r8 + i) * Cn + c0 + c];
    __syncthreads();
    #pragma unroll
    for (int i = 0; i < 32; i += 8)
        out[(size_t)(c0 + r8 + i) * R + r0 + c] = f2bf(tile[c][r8 + i]);
}

// =================== 256x256 8-wave 8-phase/2-K-tile GEMM ==================
// Faithful m201-template port. Even K-tiles live in buf0, odd in buf1.
// Phase = {ds_read subtile; stage half-tile; barrier; lgkmcnt(0);
//          setprio(1) 16xMFMA setprio(0); barrier}.
// vmcnt(4) only at P4/P8 tops. af ping-pong (aflo/afhi) so P4/P8 pre-read
// the NEXT tile's A-mh0 after the vmcnt+barrier (cross-wave safe).

#define WAITV(N) asm volatile("s_waitcnt vmcnt(" #N ")" ::: "memory")
#define LGKM0()  asm volatile("s_waitcnt lgkmcnt(0)" ::: "memory")
#define BAR()    do { asm volatile("" ::: "memory"); \
                      __builtin_amdgcn_s_barrier();  \
                      asm volatile("" ::: "memory"); } while (0)

__device__ __forceinline__ void gll(const unsigned short* src, unsigned short* dst) {
    __builtin_amdgcn_global_load_lds(
        (const __attribute__((address_space(1))) void*)src,
        (__attribute__((address_space(3))) void*)dst, 16, 0, 0);
}

// A sub 0 = rows {[0,64) u [128,192)} (mh0 rows of both wm); sub 1 = +64.
__device__ __forceinline__ void stage_a(const unsigned short* Ag, int K, int k0,
                                        unsigned short* lds, int sub,
                                        int wid, int lane) {
    const int rl = wid * 8 + (lane >> 3);
    const int ce = ((lane & 7) ^ (lane >> 3)) * 8;   // inverse-swizzled col
    #pragma unroll
    for (int j = 0; j < 2; ++j) {
        int row = j * 128 + sub * 64;
        gll(Ag + (size_t)(row + rl) * K + k0 + ce,
            lds + (row + wid * 8) * 64);
    }
}
// B sub 0 = rows {wn*64+[0,32)} all wn (nh0); sub 1 = +32 (nh1).
__device__ __forceinline__ void stage_b(const unsigned short* Bg, int K, int k0,
                                        unsigned short* lds, int sub,
                                        int wid, int lane) {
    const int ce = ((lane & 7) ^ (lane >> 3)) * 8;
    const int rb = (wid >> 2) * 64 + sub * 32 + (wid & 3) * 8;
    #pragma unroll
    for (int j = 0; j < 2; ++j) {
        int rowbase = j * 128 + rb;
        gll(Bg + (size_t)(rowbase + (lane >> 3)) * K + k0 + ce,
            lds + rowbase * 64);
    }
}

__device__ __forceinline__ bf16x8 ld_frag(const unsigned short* tile,
                                          int r, int kk, int fq) {
    int slot = (kk * 4 + fq) ^ (r & 7);          // swizzled 16B slot
    return *reinterpret_cast<const bf16x8*>(tile + r * 64 + slot * 8);
}

template <int MH>
__device__ __forceinline__ void read_a(const unsigned short* T, int wm,
                                       int fr, int fq, bf16x8 af[4][2]) {
    #pragma unroll
    for (int m = 0; m < 4; ++m) {
        int r = wm * 128 + MH * 64 + m * 16 + fr;
        af[m][0] = ld_frag(T, r, 0, fq);
        af[m][1] = ld_frag(T, r, 1, fq);
    }
}
template <int NHH>
__device__ __forceinline__ void read_b(const unsigned short* T, int wn,
                                       int fr, int fq, bf16x8 bfr[4][2]) {
    #pragma unroll
    for (int n = 0; n < 2; ++n) {
        int r = wn * 64 + NHH * 32 + n * 16 + fr;
        bfr[NHH * 2 + n][0] = ld_frag(T, r, 0, fq);
        bfr[NHH * 2 + n][1] = ld_frag(T, r, 1, fq);
    }
}

template <int MH, int NHH>
__device__ __forceinline__ void mfma_quad(f32x4 acc[8][4],
                                          const bf16x8 af[4][2],
                                          const bf16x8 bfr[4][2]) {
    __builtin_amdgcn_s_setprio(1);
    #pragma unroll
    for (int kk = 0; kk < 2; ++kk)
        #pragma unroll
        for (int m = 0; m < 4; ++m)
            #pragma unroll
            for (int n = 0; n < 2; ++n)
                acc[MH * 4 + m][NHH * 2 + n] =
                    __builtin_amdgcn_mfma_f32_16x16x32_bf16(
                        af[m][kk], bfr[NHH * 2 + n][kk],
                        acc[MH * 4 + m][NHH * 2 + n], 0, 0, 0);
    __builtin_amdgcn_s_setprio(0);
}

template <typename OUT_T>
__global__ __launch_bounds__(512, 2) void gemm256(
        const unsigned short* __restrict__ A,   // [M][K] bf16
        const unsigned short* __restrict__ Bt,  // [N][K] bf16
        OUT_T* __restrict__ C,                  // [M][N]
        int M, int N, int K, int nbx, int cpx) {
    __shared__ unsigned short As[2][256 * 64];
    __shared__ unsigned short Bs[2][256 * 64];

    const int bid = blockIdx.x;
    const int wk  = (bid & 7) * cpx + (bid >> 3);   // T1 XCD swizzle
    const int bx  = wk % nbx, by = wk / nbx;
    const int tid = threadIdx.x, wid = tid >> 6, lane = tid & 63;
    const int wm  = wid >> 2, wn = wid & 3;
    const int fr  = lane & 15, fq = lane >> 4;

    const unsigned short* Ag = A  + (size_t)by * 256 * K;
    const unsigned short* Bg = Bt + (size_t)bx * 256 * K;

    f32x4 acc[8][4] = {};
    bf16x8 aflo[4][2], afhi[4][2], bfr[4][2];

    // prologue: stage tiles 0 (buf0) and 1 (buf1) fully; 16 loads
    stage_b(Bg, K, 0, Bs[0], 0, wid, lane);
    stage_b(Bg, K, 0, Bs[0], 1, wid, lane);
    stage_a(Ag, K, 0, As[0], 1, wid, lane);
    stage_a(Ag, K, 0, As[0], 0, wid, lane);
    stage_b(Bg, K, 64, Bs[1], 0, wid, lane);
    stage_b(Bg, K, 64, Bs[1], 1, wid, lane);
    stage_a(Ag, K, 64, As[1], 1, wid, lane);
    stage_a(Ag, K, 64, As[1], 0, wid, lane);
    WAITV(8);                                  // tile 0 landed (own wave)
    BAR();                                     // -> landed for all waves
    read_a<0>(As[0], wm, fr, fq, aflo);        // pre-read A-mh0(tile0)

    const int NK = K / 64;
    for (int k = 0; k < NK / 2 - 1; ++k) {
        const int kA = (2 * k + 2) * 64;       // stage tile -> buf0
        const int kB = (2 * k + 3) * 64;       // stage tile -> buf1
        // ---- P1: quad(0,0) of T0
        read_b<0>(Bs[0], wn, fr, fq, bfr);
        BAR(); LGKM0();
        mfma_quad<0, 0>(acc, aflo, bfr);
        BAR();
        // ---- P2
        read_b<1>(Bs[0], wn, fr, fq, bfr);
        stage_b(Bg, K, kA, Bs[0], 0, wid, lane);
        BAR(); LGKM0();
        mfma_quad<0, 1>(acc, aflo, bfr);
        BAR();
        // ---- P3
        read_a<1>(As[0], wm, fr, fq, afhi);
        stage_b(Bg, K, kA, Bs[0], 1, wid, lane);
        BAR(); LGKM0();
        mfma_quad<1, 1>(acc, afhi, bfr);
        BAR();
        // ---- P4: wait lands tile T1 (odd) fully for all waves
        WAITV(4);
        stage_a(Ag, K, kA, As[0], 1, wid, lane);
        stage_a(Ag, K, kA, As[0], 0, wid, lane);
        BAR();
        read_a<0>(As[1], wm, fr, fq, aflo);    // pre-read A-mh0(T1)
        mfma_quad<1, 0>(acc, afhi, bfr);
        BAR();
        // ---- P5: quad(0,0) of T1
        read_b<0>(Bs[1], wn, fr, fq, bfr);
        BAR(); LGKM0();
        mfma_quad<0, 0>(acc, aflo, bfr);
        BAR();
        // ---- P6
        read_b<1>(Bs[1], wn, fr, fq, bfr);
        stage_b(Bg, K, kB, Bs[1], 0, wid, lane);
        BAR(); LGKM0();
        mfma_quad<0, 1>(acc, aflo, bfr);
        BAR();
        // ---- P7
        read_a<1>(As[1], wm, fr, fq, afhi);
        stage_b(Bg, K, kB, Bs[1], 1, wid, lane);
        BAR(); LGKM0();
        mfma_quad<1, 1>(acc, afhi, bfr);
        BAR();
        // ---- P8: wait lands tile T0+2 (buf0) fully for all waves
        WAITV(4);
        stage_a(Ag, K, kB, As[1], 1, wid, lane);
        stage_a(Ag, K, kB, As[1], 0, wid, lane);
        BAR();
        read_a<0>(As[0], wm, fr, fq, aflo);    // pre-read A-mh0(T0+2)
        mfma_quad<1, 0>(acc, afhi, bfr);
        BAR();
    }
    // epilogue: tiles NK-2 (buf0), NK-1 (buf1); no staging
    read_b<0>(Bs[0], wn, fr, fq, bfr);
    BAR(); LGKM0(); mfma_quad<0, 0>(acc, aflo, bfr); BAR();
    read_b<1>(Bs[0], wn, fr, fq, bfr);
    BAR(); LGKM0(); mfma_quad<0, 1>(acc, aflo, bfr); BAR();
    read_a<1>(As[0], wm, fr, fq, afhi);
    BAR(); LGKM0(); mfma_quad<1, 1>(acc, afhi, bfr); BAR();
    WAITV(0); BAR();                            // land tile NK-1 fully
    read_a<0>(As[1], wm, fr, fq, aflo);
    mfma_quad<1, 0>(acc, afhi, bfr); BAR();
    read_b<0>(Bs[1], wn, fr, fq, bfr);
    BAR(); LGKM0(); mfma_quad<0, 0>(acc, aflo, bfr); BAR();
    read_b<1>(Bs[1], wn, fr, fq, bfr);
    BAR(); LGKM0(); mfma_quad<0, 1>(acc, aflo, bfr); BAR();
    read_a<1>(As[1], wm, fr, fq, afhi);
    BAR(); LGKM0(); mfma_quad<1, 1>(acc, afhi, bfr); BAR();
    mfma_quad<1, 0>(acc, afhi, bfr);

    // epilogue C write (verified C/D layout: row = fq*4+r, col = fr)
    const int bm = by * 256, bn = bx * 256;
    #pragma unroll
    for (int m = 0; m < 8; ++m) {
        #pragma unroll
        for (int n = 0; n < 4; ++n) {
            #pragma unroll
            for (int r = 0; r < 4; ++r) {
                int row = bm + wm * 128 + m * 16 + fq * 4 + r;
                int col = bn + wn * 64 + n * 16 + fr;
                float v = acc[m][n][r];
                if constexpr (sizeof(OUT_T) == 2)
                    C[(size_t)row * N + col] = (OUT_T)f2bf(v);
                else
                    C[(size_t)row * N + col] = (OUT_T)v;
            }
        }
    }
}

// ---------------- scan helpers ----------------
__device__ inline float phi_f(float z) { return z > 0.f ? z + 1.f : __expf(z); }
__device__ inline float sigmoid_f(float z) { return 1.f / (1.f + __expf(-z)); }

// Pass 1: per-(b,h,chunk) local scan finals (zero init). qkv bf16.
// lane owns dims {2*lane, 2*lane+1} (paired 4B loads).
__global__ void scan_pass1(const unsigned short* __restrict__ qkv,
                           const float* __restrict__ decay_param,
                           float* __restrict__ fkv, float* __restrict__ fk) {
    const int blk = blockIdx.x;
    const int c = blk % NCH;
    const int h = (blk / NCH) % NH;
    const int b = blk / (NCH * NH);
    const int lane = threadIdx.x;
    const float dec = sigmoid_f(decay_param[h]);

    float skv0 = 0.f, skv1 = 0.f, sk0 = 0.f, sk1 = 0.f;
    const unsigned short* base =
        qkv + ((size_t)b * NT + (size_t)c * CHUNK) * QKV_N + h * ND;
    for (int t = 0; t < CHUNK; ++t) {
        const unsigned short* r = base + (size_t)t * QKV_N;
        unsigned kp = *reinterpret_cast<const unsigned*>(r + HID + 2 * lane);
        unsigned vp = *reinterpret_cast<const unsigned*>(r + 2 * HID + 2 * lane);
        float k0 = phi_f(bf2f((unsigned short)(kp & 0xffff)));
        float k1 = phi_f(bf2f((unsigned short)(kp >> 16)));
        float v0 = bf2f((unsigned short)(vp & 0xffff));
        float v1 = bf2f((unsigned short)(vp >> 16));
        skv0 = fmaf(dec, skv0, k0 * v0);
        skv1 = fmaf(dec, skv1, k1 * v1);
        sk0  = fmaf(dec, sk0,  k0);
        sk1  = fmaf(dec, sk1,  k1);
    }
    size_t o = (size_t)blk * ND + 2 * lane;
    *reinterpret_cast<float2*>(&fkv[o]) = make_float2(skv0, skv1);
    *reinterpret_cast<float2*>(&fk[o])  = make_float2(sk0, sk1);
}

// Pass 2: sequential chunk combine; emits carry-ins and final states.
__global__ void scan_pass2(const float* __restrict__ fkv, const float* __restrict__ fk,
                           const float* __restrict__ decay_param,
                           float* __restrict__ ckv, float* __restrict__ ck,
                           float* __restrict__ out_states) {
    const int bh = blockIdx.x;
    const int h = bh % NH;
    const int lane = threadIdx.x;
    const float dec = sigmoid_f(decay_param[h]);
    const float dL = powf(dec, (float)CHUNK);

    float Skv0 = 0.f, Skv1 = 0.f, Sk0 = 0.f, Sk1 = 0.f;
    for (int c = 0; c < NCH; ++c) {
        size_t o = ((size_t)bh * NCH + c) * ND + 2 * lane;
        *reinterpret_cast<float2*>(&ckv[o]) = make_float2(Skv0, Skv1);
        *reinterpret_cast<float2*>(&ck[o])  = make_float2(Sk0, Sk1);
        float2 fv = *reinterpret_cast<const float2*>(&fkv[o]);
        float2 fs = *reinterpret_cast<const float2*>(&fk[o]);
        Skv0 = fmaf(dL, Skv0, fv.x);
        Skv1 = fmaf(dL, Skv1, fv.y);
        Sk0  = fmaf(dL, Sk0,  fs.x);
        Sk1  = fmaf(dL, Sk1,  fs.y);
    }
    size_t so = (size_t)bh * ND + 2 * lane;
    *reinterpret_cast<float2*>(&out_states[so]) = make_float2(Skv0, Skv1);
    *reinterpret_cast<float2*>(&out_states[NB * NH * ND + so]) = make_float2(Sk0, Sk1);
}

// Pass 3: replay with carry-in; writes attn in bf16.
__global__ void scan_pass3(const unsigned short* __restrict__ qkv,
                           const float* __restrict__ decay_param,
                           const float* __restrict__ ckv, const float* __restrict__ ck,
                           unsigned short* __restrict__ attn) {
    const int blk = blockIdx.x;
    const int c = blk % NCH;
    const int h = (blk / NCH) % NH;
    const int b = blk / (NCH * NH);
    const int lane = threadIdx.x;
    const float dec = sigmoid_f(decay_param[h]);

    size_t co = (size_t)blk * ND + 2 * lane;
    float2 cv = *reinterpret_cast<const float2*>(&ckv[co]);
    float2 cs = *reinterpret_cast<const float2*>(&ck[co]);
    float skv0 = cv.x, skv1 = cv.y, sk0 = cs.x, sk1 = cs.y;

    const unsigned short* base =
        qkv + ((size_t)b * NT + (size_t)c * CHUNK) * QKV_N + h * ND;
    unsigned short* abase =
        attn + ((size_t)b * NT + (size_t)c * CHUNK) * HID + h * ND;

    for (int t = 0; t < CHUNK; ++t) {
        const unsigned short* r = base + (size_t)t * QKV_N;
        unsigned qp = *reinterpret_cast<const unsigned*>(r + 2 * lane);
        unsigned kp = *reinterpret_cast<const unsigned*>(r + HID + 2 * lane);
        unsigned vp = *reinterpret_cast<const unsigned*>(r + 2 * HID + 2 * lane);
        float q0 = phi_f(bf2f((unsigned short)(qp & 0xffff)));
        float q1 = phi_f(bf2f((unsigned short)(qp >> 16)));
        float k0 = phi_f(bf2f((unsigned short)(kp & 0xffff)));
        float k1 = phi_f(bf2f((unsigned short)(kp >> 16)));
        float v0 = bf2f((unsigned short)(vp & 0xffff));
        float v1 = bf2f((unsigned short)(vp >> 16));
        skv0 = fmaf(dec, skv0, k0 * v0);
        skv1 = fmaf(dec, skv1, k1 * v1);
        sk0  = fmaf(dec, sk0,  k0);
        sk1  = fmaf(dec, sk1,  k1);
        float den = fmaf(q0, sk0, q1 * sk1);
        #pragma unroll
        for (int m = 1; m < 64; m <<= 1) den += __shfl_xor(den, m, 64);
        den = fmaxf(den, 1e-6f);
        float inv = 1.f / den;
        unsigned o = ((unsigned)f2bf(q1 * skv1 * inv) << 16) |
                     (unsigned)f2bf(q0 * skv0 * inv);
        *reinterpret_cast<unsigned*>(abase + (size_t)t * HID + 2 * lane) = o;
    }
}

// ---------------- launch ----------------
extern "C" void kernel_launch(void* const* d_in, const int* in_sizes, int n_in,
                              void* d_out, int out_size, void* d_ws, size_t ws_size,
                              hipStream_t stream) {
    const float* x      = (const float*)d_in[0];   // [2,4096,2048]
    const float* w_qkv  = (const float*)d_in[1];   // [2048,6144]
    const float* w_out  = (const float*)d_in[2];   // [2048,2048]
    const float* decayp = (const float*)d_in[3];   // [16]
    float* out = (float*)d_out;

    // workspace layout
    char* ws = (char*)d_ws;
    unsigned short* xb     = (unsigned short*)ws;                         // 8192*2048
    unsigned short* wqkvT  = xb    + (size_t)ROWS * HID;                  // 6144*2048
    unsigned short* woutT  = wqkvT + (size_t)QKV_N * HID;                 // 2048*2048
    unsigned short* qkvb   = woutT + (size_t)HID * HID;                   // 8192*6144
    unsigned short* attnb  = qkvb  + (size_t)ROWS * QKV_N;                // 8192*2048
    float* fkv = (float*)(attnb + (size_t)ROWS * HID);
    float* fk  = fkv + (size_t)NB * NH * NCH * ND;
    float* ckv = fk  + (size_t)NB * NH * NCH * ND;
    float* ck  = ckv + (size_t)NB * NH * NCH * ND;

    // casts
    cast_kernel<<<2048, 256, 0, stream>>>(x, xb, (size_t)ROWS * HID / 4);
    dim3 tg1(QKV_N / 32, HID / 32);
    transpose_cast<<<tg1, 256, 0, stream>>>(w_qkv, wqkvT, HID, QKV_N);
    dim3 tg2(HID / 32, HID / 32);
    transpose_cast<<<tg2, 256, 0, stream>>>(w_out, woutT, HID, HID);

    // GEMM1: qkvb = xb @ wqkvT^T   (bf16 out)  grid 32x24=768
    {
        int nbx = QKV_N / 256, nwg = (ROWS / 256) * nbx;
        gemm256<unsigned short><<<nwg, 512, 0, stream>>>(
            xb, wqkvT, qkvb, ROWS, QKV_N, HID, nbx, nwg / 8);
    }

    // chunked decay scans
    scan_pass1<<<NB * NH * NCH, 64, 0, stream>>>(qkvb, decayp, fkv, fk);
    scan_pass2<<<NB * NH, 64, 0, stream>>>(fkv, fk, decayp, ckv, ck,
                                           out + (size_t)ROWS * HID);
    scan_pass3<<<NB * NH * NCH, 64, 0, stream>>>(qkvb, decayp, ckv, ck, attnb);

    // GEMM2: out = attnb @ woutT^T  (f32 out)  grid 32x8=256
    {
        int nbx = HID / 256, nwg = (ROWS / 256) * nbx;
        gemm256<float><<<nwg, 512, 0, stream>>>(
            attnb, woutT, out, ROWS, HID, HID, nbx, nwg / 8);
    }
}